// Round 15
// baseline (370.084 us; speedup 1.0000x reference)
//
#include <hip/hip_runtime.h>

typedef __bf16 bf16x8 __attribute__((ext_vector_type(8)));
typedef float  f32x4  __attribute__((ext_vector_type(4)));

#define LOG2E 1.4426950408889634f

static __device__ __forceinline__ float fexp2(float x) { return __builtin_amdgcn_exp2f(x); }
static __device__ __forceinline__ float frcp(float x)  { return __builtin_amdgcn_rcpf(x); }
static __device__ __forceinline__ float fsigmoid(float x) { return frcp(1.0f + fexp2(-LOG2E * x)); }
static __device__ __forceinline__ float ftanh(float x)    { return 2.0f * frcp(1.0f + fexp2(-2.0f * LOG2E * x)) - 1.0f; }

// ---------------------------------------------------------------------------
// Prep (verified r10-r14): pack 4 [512x512] fp32 weights into bf16 16x16x32
// B-fragment order, GATE-CONTIGUOUS:
// Wp[(((cn*16+ks)*4+g)*64 + lt)*8 + e] = W_g[cn*16+(lt&15)][ks*32+(lt>>4)*8+e]
// Per (cn,ks): 4 KiB = gates 0..3 x 1 KiB, lane-linear.
// ---------------------------------------------------------------------------
__global__ __launch_bounds__(256) void wpack(const float* __restrict__ Wf,
                                             const float* __restrict__ Wi,
                                             const float* __restrict__ Wg,
                                             const float* __restrict__ Wo,
                                             __bf16* __restrict__ Wp)
{
    int idx = blockIdx.x * 256 + threadIdx.x;      // [0, 131072)
    int kg  = idx & 63;                            // k-group of 8
    int j   = (idx >> 6) & 511;                    // weight row = output col
    int g   = idx >> 15;
    const float* src = (g == 0) ? Wf : (g == 1) ? Wi : (g == 2) ? Wg : Wo;
    const float4* s4 = (const float4*)(src + j * 512 + kg * 8);
    float4 v0 = s4[0], v1 = s4[1];
    bf16x8 o;
    o[0] = (__bf16)v0.x; o[1] = (__bf16)v0.y; o[2] = (__bf16)v0.z; o[3] = (__bf16)v0.w;
    o[4] = (__bf16)v1.x; o[5] = (__bf16)v1.y; o[6] = (__bf16)v1.z; o[7] = (__bf16)v1.w;
    int cn = j >> 4;                               // 16-col group
    int ks = kg >> 2;                              // K=32 step
    int lt = (j & 15) + (kg & 3) * 16;             // lane slot
    size_t dst = ((size_t)(((cn * 16 + ks) * 4 + g) * 64 + lt)) * 8;
    *(bf16x8*)(Wp + dst) = o;
}

// ---------------------------------------------------------------------------
// Main fused kernel = r9 geometry (16 waves, BM=128, gate-split twins,
// acc = 8m x 2g x 4 = 64 AGPR, 4 waves/SIMD, B-demand 26 B/cyc/CU) with the
// 32 block-wide barriers replaced by a per-pair flag handshake:
// wave pair (wv, wv+8) shares cn; rh=1 (gates G,O) publishes pre-activations
// one m-frag at a time through a 2 KiB LDS slot; rh=0 (gates F,I) combines
// and issues ALL stores. No __syncthreads after phase 0 - pairs free-run.
// LDS: 128K z-image + 8 x 2K slots + flags = 144.2 KiB -> 1 block/CU.
// ---------------------------------------------------------------------------
__global__ __launch_bounds__(1024, 4) void lstm_main(
    const float* __restrict__ xin, const float* __restrict__ stm,
    const __bf16* __restrict__ Wp,
    const float* __restrict__ bfv, const float* __restrict__ biv,
    const float* __restrict__ bgv, const float* __restrict__ bov,
    float* __restrict__ out)
{
    __shared__ unsigned char zs[131072];           // 128 rows x 512 k, bf16, frag order
    __shared__ unsigned char xslot[8][2048];       // per-pair exchange slot
    __shared__ int pf[8];                          // published seq (per pair)
    __shared__ int ackf[8];                        // consumed seq (per pair)
    const int tid  = threadIdx.x;
    const int lane = tid & 63;
    const int wv   = tid >> 6;                     // 0..15
    const int p8   = wv & 7;                       // pair id = col group within ci
    const int rh   = wv >> 3;                      // 0: gates F,I (combiner)  1: G,O (publisher)
    const int l15  = lane & 15;
    const int lq   = lane >> 4;                    // 0..3
    const int row0 = blockIdx.x * 128;

    if (tid < 8) { pf[tid] = 0; ackf[tid] = 0; }

    // ---- phase 0: z = x + stm -> bf16 -> LDS frag image (verified r9) ----
    {
        const float* xb = xin + (size_t)row0 * 512;
        const float* sb = stm + (size_t)row0 * 512;
        #pragma unroll
        for (int it = 0; it < 8; ++it) {
            int idx = it * 1024 + tid;             // [0, 8192): 128 rows x 64 kgroups
            int row = idx >> 6;
            int kg  = idx & 63;
            const float4* x4 = (const float4*)(xb + row * 512 + kg * 8);
            const float4* s4 = (const float4*)(sb + row * 512 + kg * 8);
            float4 a0 = x4[0], a1 = x4[1];
            float4 b0 = s4[0], b1 = s4[1];
            bf16x8 p;
            p[0] = (__bf16)(a0.x + b0.x); p[1] = (__bf16)(a0.y + b0.y);
            p[2] = (__bf16)(a0.z + b0.z); p[3] = (__bf16)(a0.w + b0.w);
            p[4] = (__bf16)(a1.x + b1.x); p[5] = (__bf16)(a1.y + b1.y);
            p[6] = (__bf16)(a1.z + b1.z); p[7] = (__bf16)(a1.w + b1.w);
            int rb   = row >> 5;                   // 0..3 chunk (32 KiB each)
            int kk   = kg >> 1;
            int slot = ((row & 31) + (kg & 1) * 32) ^ (kk & 7);
            *(bf16x8*)(zs + rb * 32768 + kk * 1024 + slot * 16) = p;
        }
    }
    __syncthreads();                               // only block-wide barrier

    // A-read invariants (verified r6/r9):
    // byte = (m>>1)*32768 + (m&1)*256 + ((s0^kk7)<<4) + ks*2048 + (kkoff<<10)
    const int kkoff = lq >> 1;                     // 0/1
    const int s0    = l15 + (lq & 1) * 32;         // bit4 clear
    const int koffb = kkoff << 10;

    volatile int* vpf  = (volatile int*)&pf[p8];
    volatile int* vack = (volatile int*)&ackf[p8];
    unsigned char* slotb = &xslot[p8][0] + lane * 32;

    for (int ci = 0; ci < 4; ++ci) {
        const int cn   = ci * 8 + p8;              // 16-col group [0,32)
        const int colj = cn * 16 + l15;
        // gate-contig weights: per (cn,ks) 4 KiB; this wave's 2 gates at rh*2048
        const char* wpB = (const char*)Wp + (size_t)cn * 65536 + rh * 2048 + (size_t)lane * 16;

        float biasA = (rh ? bgv : bfv)[colj];
        float biasB = (rh ? bov : biv)[colj];
        f32x4 acc[8][2];                           // [m][gate] = 64 AGPR
        #pragma unroll
        for (int m = 0; m < 8; ++m) {
            #pragma unroll
            for (int r = 0; r < 4; ++r) { acc[m][0][r] = biasA; acc[m][1][r] = biasB; }
        }

        #pragma unroll 2
        for (int ks = 0; ks < 16; ++ks) {
            const int kk7 = ((2 * ks) & 7) | kkoff;
            const int t0  = ((s0 ^ kk7) << 4) + ks * 2048 + koffb;
            bf16x8 b0 = *(const bf16x8*)(wpB + ks * 4096);
            bf16x8 b1 = *(const bf16x8*)(wpB + ks * 4096 + 1024);
            bf16x8 a[8];
            #pragma unroll
            for (int m = 0; m < 8; ++m)
                a[m] = *(const bf16x8*)(zs + (m >> 1) * 32768 + (m & 1) * 256 + t0);
            __builtin_amdgcn_s_setprio(1);
            #pragma unroll
            for (int m = 0; m < 8; ++m) {
                acc[m][0] = __builtin_amdgcn_mfma_f32_16x16x32_bf16(a[m], b0, acc[m][0], 0, 0, 0);
                acc[m][1] = __builtin_amdgcn_mfma_f32_16x16x32_bf16(a[m], b1, acc[m][1], 0, 0, 0);
            }
            __builtin_amdgcn_s_setprio(0);
        }

        // ---- pairwise epilogue, no block barrier ----
        if (rh == 1) {
            // publisher: hand (G,O)[m] to the twin, one m per round-trip
            #pragma unroll 1
            for (int m = 0; m < 8; ++m) {
                const int seq = ci * 8 + m + 1;
                while (*vack < seq - 1) __builtin_amdgcn_s_sleep(1);
                asm volatile("" ::: "memory");
                *(f32x4*)(slotb)      = acc[m][0];     // G
                *(f32x4*)(slotb + 16) = acc[m][1];     // O
                asm volatile("s_waitcnt lgkmcnt(0)" ::: "memory");
                if (lane == 0) *vpf = seq;
            }
        } else {
            // combiner: receive (G,O)[m], combine with own (F,I)[m], store c,h
            #pragma unroll 1
            for (int m = 0; m < 8; ++m) {
                const int seq = ci * 8 + m + 1;
                while (*vpf < seq) __builtin_amdgcn_s_sleep(1);
                asm volatile("" ::: "memory");
                __builtin_amdgcn_sched_barrier(0);
                f32x4 vG = *(const f32x4*)(slotb);
                f32x4 vO = *(const f32x4*)(slotb + 16);
                asm volatile("s_waitcnt lgkmcnt(0)" ::: "memory");
                if (lane == 0) *vack = seq;            // slot free (data in regs)
                #pragma unroll
                for (int r = 0; r < 4; ++r) {
                    float c = fsigmoid(acc[m][0][r]) + fsigmoid(acc[m][1][r]) * ftanh(vG[r]);
                    float h = ftanh(c) * fsigmoid(vO[r]);
                    int row = row0 + m * 16 + lq * 4 + r;
                    int o   = row * 512 + colj;
                    out[o] = c;
                    out[33554432 + o] = h;             // h plane at 65536*512
                }
            }
        }
    }
}

extern "C" void kernel_launch(void* const* d_in, const int* in_sizes, int n_in,
                              void* d_out, int out_size, void* d_ws, size_t ws_size,
                              hipStream_t stream) {
    const float* xin = (const float*)d_in[0];
    const float* stm = (const float*)d_in[1];
    const float* Wf  = (const float*)d_in[2];
    const float* bf_ = (const float*)d_in[3];
    const float* Wi  = (const float*)d_in[4];
    const float* bi_ = (const float*)d_in[5];
    const float* Wg  = (const float*)d_in[6];
    const float* bg_ = (const float*)d_in[7];
    const float* Wo  = (const float*)d_in[8];
    const float* bo_ = (const float*)d_in[9];
    __bf16* Wp = (__bf16*)d_ws;                    // 2 MiB packed weights

    wpack<<<512, 256, 0, stream>>>(Wf, Wi, Wg, Wo, Wp);
    lstm_main<<<512, 1024, 0, stream>>>(xin, stm, Wp, bf_, bi_, bg_, bo_, (float*)d_out);
}

// Round 16
// 191.201 us; speedup vs baseline: 1.9356x; 1.9356x over previous
//
#include <hip/hip_runtime.h>

typedef __bf16 bf16x8 __attribute__((ext_vector_type(8)));
typedef float  f32x4  __attribute__((ext_vector_type(4)));

#define LOG2E 1.4426950408889634f

static __device__ __forceinline__ float fexp2(float x) { return __builtin_amdgcn_exp2f(x); }
static __device__ __forceinline__ float frcp(float x)  { return __builtin_amdgcn_rcpf(x); }
static __device__ __forceinline__ float fsigmoid(float x) { return frcp(1.0f + fexp2(-LOG2E * x)); }
static __device__ __forceinline__ float ftanh(float x)    { return 2.0f * frcp(1.0f + fexp2(-2.0f * LOG2E * x)) - 1.0f; }

// ---------------------------------------------------------------------------
// Prep (verified r10-r15): pack 4 [512x512] fp32 weights into bf16 16x16x32
// B-fragment order, GATE-CONTIGUOUS:
// Wp[(((cn*16+ks)*4+g)*64 + lt)*8 + e] = W_g[cn*16+(lt&15)][ks*32+(lt>>4)*8+e]
// Per (cn,ks): 4 KiB = 4 gates x 1 KiB, lane-linear.
// ---------------------------------------------------------------------------
__global__ __launch_bounds__(256) void wpack(const float* __restrict__ Wf,
                                             const float* __restrict__ Wi,
                                             const float* __restrict__ Wg,
                                             const float* __restrict__ Wo,
                                             __bf16* __restrict__ Wp)
{
    int idx = blockIdx.x * 256 + threadIdx.x;      // [0, 131072)
    int kg  = idx & 63;                            // k-group of 8
    int j   = (idx >> 6) & 511;                    // weight row = output col
    int g   = idx >> 15;
    const float* src = (g == 0) ? Wf : (g == 1) ? Wi : (g == 2) ? Wg : Wo;
    const float4* s4 = (const float4*)(src + j * 512 + kg * 8);
    float4 v0 = s4[0], v1 = s4[1];
    bf16x8 o;
    o[0] = (__bf16)v0.x; o[1] = (__bf16)v0.y; o[2] = (__bf16)v0.z; o[3] = (__bf16)v0.w;
    o[4] = (__bf16)v1.x; o[5] = (__bf16)v1.y; o[6] = (__bf16)v1.z; o[7] = (__bf16)v1.w;
    int cn = j >> 4;                               // 16-col group
    int ks = kg >> 2;                              // K=32 step
    int lt = (j & 15) + (kg & 3) * 16;             // lane slot
    size_t dst = ((size_t)(((cn * 16 + ks) * 4 + g) * 64 + lt)) * 8;
    *(bf16x8*)(Wp + dst) = o;
}

// ---------------------------------------------------------------------------
// Main fused kernel = r6 skeleton (best baseline) + wave phase-skew + setprio.
// Block: 512 thr (8 waves), BM=128 rows, 128 KiB LDS, 1 block/CU, 2 waves/SIMD.
// Each wave owns ALL 128 rows x 16 cols x 4 gates (acc = 8m x 4g x 4 = 128).
// After the phase-0 barrier each wave sleeps ~192*wv cycles: same-SIMD waves
// become anti-phased, so one wave's B/A load stalls and epilogue VALU overlap
// the partner wave's MFMA burst (no later barrier ever re-syncs them).
// ---------------------------------------------------------------------------
__global__ __launch_bounds__(512, 2) void lstm_main(
    const float* __restrict__ xin, const float* __restrict__ stm,
    const __bf16* __restrict__ Wp,
    const float* __restrict__ bfv, const float* __restrict__ biv,
    const float* __restrict__ bgv, const float* __restrict__ bov,
    float* __restrict__ out)
{
    __shared__ unsigned char zs[131072];           // 128 rows x 512 k, bf16, frag order
    const int tid  = threadIdx.x;
    const int lane = tid & 63;
    const int wv   = tid >> 6;                     // 0..7
    const int l15  = lane & 15;
    const int lq   = lane >> 4;                    // 0..3
    const int row0 = blockIdx.x * 128;

    // ---- phase 0: z = x + stm -> bf16 -> LDS in frag order (verified r6) ----
    {
        const float* xb = xin + (size_t)row0 * 512;
        const float* sb = stm + (size_t)row0 * 512;
        #pragma unroll
        for (int it = 0; it < 16; ++it) {
            int idx = it * 512 + tid;              // [0, 8192): 128 rows x 64 kgroups
            int row = idx >> 6;
            int kg  = idx & 63;
            const float4* x4 = (const float4*)(xb + row * 512 + kg * 8);
            const float4* s4 = (const float4*)(sb + row * 512 + kg * 8);
            float4 a0 = x4[0], a1 = x4[1];
            float4 b0 = s4[0], b1 = s4[1];
            bf16x8 p;
            p[0] = (__bf16)(a0.x + b0.x); p[1] = (__bf16)(a0.y + b0.y);
            p[2] = (__bf16)(a0.z + b0.z); p[3] = (__bf16)(a0.w + b0.w);
            p[4] = (__bf16)(a1.x + b1.x); p[5] = (__bf16)(a1.y + b1.y);
            p[6] = (__bf16)(a1.z + b1.z); p[7] = (__bf16)(a1.w + b1.w);
            int rb   = row >> 5;                   // 0..3 chunk (32 KiB each)
            int kk   = kg >> 1;
            int slot = ((row & 31) + (kg & 1) * 32) ^ (kk & 7);
            *(bf16x8*)(zs + rb * 32768 + kk * 1024 + slot * 16) = p;
        }
    }
    __syncthreads();                               // only barrier

    // ---- deliberate wave phase-skew: ~192 cyc per wave index ----
    for (int i = 0; i < wv; ++i) __builtin_amdgcn_s_sleep(3);

    // A-read invariants (verified r6):
    const int kkoff = lq >> 1;                     // 0/1
    const int sl0   = l15 + (lq & 1) * 32;         // bit4 clear
    const int koffb = kkoff << 10;

    // ---- phase 1: column loop, no barriers ----
    for (int ci = 0; ci < 4; ++ci) {
        const int cn   = ci * 8 + wv;              // 16-col group [0,32)
        const int colj = cn * 16 + l15;
        const __bf16* bp = Wp + (size_t)cn * 32768 + lane * 8;  // gate-contig base

        float bias0 = bfv[colj], bias1 = biv[colj];
        float bias2 = bgv[colj], bias3 = bov[colj];
        f32x4 acc[8][4];                           // [m][gate] = 128 regs
        #pragma unroll
        for (int m = 0; m < 8; ++m) {
            #pragma unroll
            for (int r = 0; r < 4; ++r) {
                acc[m][0][r] = bias0; acc[m][1][r] = bias1;
                acc[m][2][r] = bias2; acc[m][3][r] = bias3;
            }
        }

        #pragma unroll 2
        for (int ks = 0; ks < 16; ++ks) {
            const int kk7 = ((2 * ks) & 7) | kkoff;
            const int t0  = ((sl0 ^ kk7) << 4) + ks * 2048 + koffb;
            const __bf16* p_ = bp + ks * 2048;
            bf16x8 b0 = *(const bf16x8*)(p_);
            bf16x8 b1 = *(const bf16x8*)(p_ + 512);
            bf16x8 b2 = *(const bf16x8*)(p_ + 1024);
            bf16x8 b3 = *(const bf16x8*)(p_ + 1536);
            bf16x8 a[8];
            #pragma unroll
            for (int m = 0; m < 8; ++m)
                a[m] = *(const bf16x8*)(zs + (m >> 1) * 32768 + (m & 1) * 256 + t0);
            __builtin_amdgcn_s_setprio(1);
            #pragma unroll
            for (int m = 0; m < 8; ++m) {
                acc[m][0] = __builtin_amdgcn_mfma_f32_16x16x32_bf16(a[m], b0, acc[m][0], 0, 0, 0);
                acc[m][1] = __builtin_amdgcn_mfma_f32_16x16x32_bf16(a[m], b1, acc[m][1], 0, 0, 0);
                acc[m][2] = __builtin_amdgcn_mfma_f32_16x16x32_bf16(a[m], b2, acc[m][2], 0, 0, 0);
                acc[m][3] = __builtin_amdgcn_mfma_f32_16x16x32_bf16(a[m], b3, acc[m][3], 0, 0, 0);
            }
            __builtin_amdgcn_s_setprio(0);
        }

        // ---- epilogue (verified r6): col = l&15, row = lq*4 + r ----
        #pragma unroll
        for (int m = 0; m < 8; ++m) {
            #pragma unroll
            for (int r = 0; r < 4; ++r) {
                float F = acc[m][0][r], I = acc[m][1][r];
                float G = acc[m][2][r], O = acc[m][3][r];
                float c = fsigmoid(F) + fsigmoid(I) * ftanh(G);
                float h = ftanh(c) * fsigmoid(O);
                int row = row0 + m * 16 + lq * 4 + r;
                int o   = row * 512 + colj;
                out[o] = c;
                out[33554432 + o] = h;             // h plane at 65536*512
            }
        }
    }
}

extern "C" void kernel_launch(void* const* d_in, const int* in_sizes, int n_in,
                              void* d_out, int out_size, void* d_ws, size_t ws_size,
                              hipStream_t stream) {
    const float* xin = (const float*)d_in[0];
    const float* stm = (const float*)d_in[1];
    const float* Wf  = (const float*)d_in[2];
    const float* bf_ = (const float*)d_in[3];
    const float* Wi  = (const float*)d_in[4];
    const float* bi_ = (const float*)d_in[5];
    const float* Wg  = (const float*)d_in[6];
    const float* bg_ = (const float*)d_in[7];
    const float* Wo  = (const float*)d_in[8];
    const float* bo_ = (const float*)d_in[9];
    __bf16* Wp = (__bf16*)d_ws;                    // 2 MiB packed weights

    wpack<<<512, 256, 0, stream>>>(Wf, Wi, Wg, Wo, Wp);
    lstm_main<<<512, 512, 0, stream>>>(xin, stm, Wp, bf_, bi_, bg_, bo_, (float*)d_out);
}